// Round 2
// baseline (313.234 us; speedup 1.0000x reference)
//
#include <hip/hip_runtime.h>
#include <stdint.h>

#define B_   32
#define T_   2048
#define V_   50000
#define WD_  300
#define P_   150
#define KP   320      // K padded (300 -> 320)
#define MP   2112     // M padded (2100 -> 2112)
#define NPAD 50048    // V padded to 128-multiple
#define CHUNK 64
#define NCH   32
#define NEGC (-1.0e30f)

// workspace layout (bytes)
#define WS_EMBT      0u                      // 50048*320*2 = 32,030,720  (reused as chunkout later)
#define WS_DIAGSB    32030720u               // 2112*320*2  =  1,351,680
#define WS_TRANS     33382400u               // 50000*2112*2 = 211,200,000
#define WS_CHUNKOUT  0u                      // 32*32*150*44*4 = 27,033,600 (aliases embT, safe: gemm done)
#define WS_NEEDED    244582400u

typedef __attribute__((ext_vector_type(8))) short bf16x8;
typedef __attribute__((ext_vector_type(4))) float f32x4;

__device__ __forceinline__ unsigned short f2bf(float f){
  unsigned u = __builtin_bit_cast(unsigned, f);
  u = u + 0x7fffu + ((u >> 16) & 1u);   // RNE
  return (unsigned short)(u >> 16);
}
__device__ __forceinline__ float bf_lo(unsigned u){ return __builtin_bit_cast(float, u << 16); }
__device__ __forceinline__ float bf_hi(unsigned u){ return __builtin_bit_cast(float, u & 0xffff0000u); }

// ---------------- K0a: emb [300][50000] f32 -> embT bf16 [NPAD][KP] (transposed, zero-padded)
__global__ __launch_bounds__(256) void k_transpose_emb(const float* __restrict__ emb,
                                                       unsigned short* __restrict__ embT){
  __shared__ float tile[32][33];
  int v0 = blockIdx.x * 32, k0 = blockIdx.y * 32;
  int tid = threadIdx.x;
  int vv = tid & 31;
  #pragma unroll
  for (int it = 0; it < 4; ++it){
    int kk = (tid >> 5) + it * 8;
    int k = k0 + kk, v = v0 + vv;
    float val = 0.f;
    if (k < WD_ && v < V_) val = emb[(size_t)k * V_ + v];
    tile[kk][vv] = val;
  }
  __syncthreads();
  int vv2 = tid >> 3, kq = tid & 7;
  unsigned short a = f2bf(tile[kq*4+0][vv2]);
  unsigned short b = f2bf(tile[kq*4+1][vv2]);
  unsigned short c = f2bf(tile[kq*4+2][vv2]);
  unsigned short d = f2bf(tile[kq*4+3][vv2]);
  uint2 pk;
  pk.x = (unsigned)a | ((unsigned)b << 16);
  pk.y = (unsigned)c | ((unsigned)d << 16);
  *(uint2*)&embT[(size_t)(v0 + vv2) * KP + k0 + kq*4] = pk;
}

// ---------------- K0b: diags [2100][300] f32 -> bf16 [MP][KP] zero-padded
__global__ __launch_bounds__(256) void k_conv_diags(const float* __restrict__ diags,
                                                    unsigned short* __restrict__ diagsB){
  int gid = blockIdx.x * 256 + threadIdx.x;   // 0 .. 2112*80-1
  int m = gid / 80;
  int k4 = (gid % 80) * 4;
  unsigned short e[4];
  #pragma unroll
  for (int i = 0; i < 4; ++i){
    int k = k4 + i;
    float v = (m < 2100 && k < WD_) ? diags[m * WD_ + k] : 0.f;
    e[i] = f2bf(v);
  }
  uint2 pk;
  pk.x = (unsigned)e[0] | ((unsigned)e[1] << 16);
  pk.y = (unsigned)e[2] | ((unsigned)e[3] << 16);
  *(uint2*)&diagsB[(size_t)m * KP + k4] = pk;
}

// ---------------- K1: trans[v][m] = sum_k embT[v][k]*diagsB[m][k] + bias[m], bf16 out
// block tile: 128 v x 64 m, 4 waves (2v x 2m), K-step 32, mfma 16x16x32 bf16
__global__ __launch_bounds__(256) void k_gemm(const unsigned short* __restrict__ embT,
                                              const unsigned short* __restrict__ diagsB,
                                              const float* __restrict__ bias,
                                              unsigned short* __restrict__ trans){
  __shared__ char smem[33792];   // stage: A 128x80B (10240) + B 64x80B (5120); epilogue: f32 [128][66]
  int bx = blockIdx.x;
  int mt = bx % 33, vt = bx / 33;
  int m0 = mt * 64, v0 = vt * 128;
  int tid = threadIdx.x;
  int lane = tid & 63, wid = tid >> 6;
  int wv = wid & 1, wm = wid >> 1;
  int lrow = lane & 15, lq = lane >> 4;

  f32x4 acc[4][2];
  #pragma unroll
  for (int i = 0; i < 4; ++i)
    #pragma unroll
    for (int j = 0; j < 2; ++j)
      acc[i][j] = (f32x4){0.f, 0.f, 0.f, 0.f};

  for (int kt = 0; kt < 10; ++kt){
    int k0 = kt * 32;
    // stage A: 128 rows x 64B (pad to 80B rows)
    #pragma unroll
    for (int u2 = 0; u2 < 2; ++u2){
      int u = tid + u2 * 256;
      int row = u >> 2, q = u & 3;
      uint4 val = *(const uint4*)&embT[(size_t)(v0 + row) * KP + k0 + q*8];
      *(uint4*)(smem + row*80 + q*16) = val;
    }
    // stage B: 64 rows x 64B
    {
      int row = tid >> 2, q = tid & 3;
      uint4 val = *(const uint4*)&diagsB[(size_t)(m0 + row) * KP + k0 + q*8];
      *(uint4*)(smem + 10240 + row*80 + q*16) = val;
    }
    __syncthreads();
    bf16x8 av[4], bv[2];
    #pragma unroll
    for (int i = 0; i < 4; ++i){
      int row = wv*64 + i*16 + lrow;
      av[i] = *(const bf16x8*)(smem + row*80 + lq*16);
    }
    #pragma unroll
    for (int j = 0; j < 2; ++j){
      int row = wm*32 + j*16 + lrow;
      bv[j] = *(const bf16x8*)(smem + 10240 + row*80 + lq*16);
    }
    #pragma unroll
    for (int i = 0; i < 4; ++i)
      #pragma unroll
      for (int j = 0; j < 2; ++j)
        acc[i][j] = __builtin_amdgcn_mfma_f32_16x16x32_bf16(av[i], bv[j], acc[i][j], 0, 0, 0);
    __syncthreads();
  }

  // epilogue: acc -> LDS f32 tile -> bias add -> bf16 coalesced store
  float* C = (float*)smem;
  #pragma unroll
  for (int i = 0; i < 4; ++i)
    #pragma unroll
    for (int j = 0; j < 2; ++j)
      #pragma unroll
      for (int r = 0; r < 4; ++r){
        int row = wv*64 + i*16 + lq*4 + r;
        int col = wm*32 + j*16 + lrow;
        C[row*66 + col] = acc[i][j][r];
      }
  __syncthreads();
  #pragma unroll
  for (int it = 0; it < 4; ++it){
    int u = tid + it * 256;
    int row = u >> 3, mc = u & 7;
    int vg = v0 + row;
    if (vg < V_){
      unsigned short e[8];
      #pragma unroll
      for (int c = 0; c < 8; ++c){
        int mg = m0 + mc*8 + c;
        float val = C[row*66 + mc*8 + c] + ((mg < 2100) ? bias[mg] : 0.f);
        e[c] = f2bf(val);
      }
      uint4 pk;
      pk.x = (unsigned)e[0] | ((unsigned)e[1] << 16);
      pk.y = (unsigned)e[2] | ((unsigned)e[3] << 16);
      pk.z = (unsigned)e[4] | ((unsigned)e[5] << 16);
      pk.w = (unsigned)e[6] | ((unsigned)e[7] << 16);
      *(uint4*)&trans[(size_t)vg * MP + m0 + mc*8] = pk;
    }
  }
}

// ---------------- K3: chunked affine max-plus scan
// per (b, chunk, p): fold 64 steps into (A cols tri-28, b 7, u 7, w 1) -> chunkout[...][44]
__global__ __launch_bounds__(192) void k_scan(const unsigned short* __restrict__ trans,
                                              const int* __restrict__ docs,
                                              const int* __restrict__ doc_lens,
                                              const float* __restrict__ epsilon,
                                              float* __restrict__ chunkout){
  __shared__ int sdocs[CHUNK];
  int b = blockIdx.x >> 5, ch = blockIdx.x & 31;
  int tid = threadIdx.x;
  if (tid < CHUNK) sdocs[tid] = docs[b * T_ + ch * CHUNK + tid];
  __syncthreads();
  int p = tid;
  if (p >= P_) return;
  int doclen = doc_lens[b];
  float eps_r[6];
  #pragma unroll
  for (int i = 0; i < 6; ++i) eps_r[i] = epsilon[p*6 + i];
  int endsel = p / 50;   // 0,1,2 -> end state 4,5,6

  float col[7][7], bvec[7], uvec[7], w;
  #pragma unroll
  for (int j = 0; j < 7; ++j)
    #pragma unroll
    for (int l = 0; l < 7; ++l) col[j][l] = (j == l) ? 0.f : NEGC;
  #pragma unroll
  for (int l = 0; l < 7; ++l){ bvec[l] = NEGC; uvec[l] = NEGC; }
  w = NEGC;

  const char* transB = (const char*)trans;

  auto step = [&](const unsigned* q, bool act){
    float tsf[7], tmn[6];
    tsf[0]=bf_lo(q[0]); tsf[1]=bf_hi(q[0]);
    tsf[2]=bf_lo(q[1]); tsf[3]=bf_hi(q[1]);
    tsf[4]=bf_lo(q[2]); tsf[5]=bf_hi(q[2]);
    tsf[6]=bf_lo(q[3]); tmn[0]=bf_hi(q[3]);
    tmn[1]=bf_lo(q[4]); tmn[2]=bf_hi(q[4]);
    tmn[3]=bf_lo(q[5]); tmn[4]=bf_hi(q[5]);
    tmn[5]=bf_lo(q[6]);
    // linear part: update each (triangular) column, descending l so old values are read
    #pragma unroll
    for (int j = 0; j < 7; ++j){
      #pragma unroll
      for (int l = 6; l >= 1; --l){
        if (l < j) continue;
        if (l == j){ col[j][l] = col[j][l] + tsf[l]; continue; }
        float ae;
        if (l - 1 == j) ae = col[j][l-1];
        else ae = fmaxf(col[j][l-1], col[j][l-2] + eps_r[l-2]);
        col[j][l] = fmaxf(ae + tmn[l-1], col[j][l] + tsf[l]);
      }
      if (j == 0) col[0][0] += tsf[0];
    }
    // const part: full reference map incl. restart(0) and zero_pad(-100)
    #pragma unroll
    for (int l = 6; l >= 1; --l){
      float ae;
      if (l == 1) ae = fmaxf(bvec[0], -100.0f);
      else ae = fmaxf(bvec[l-1], bvec[l-2] + eps_r[l-2]);
      bvec[l] = fmaxf(ae + tmn[l-1], bvec[l] + tsf[l]);
    }
    bvec[0] = fmaxf(0.0f, bvec[0] + tsf[0]);
    if (act){
      #pragma unroll
      for (int j = 0; j < 7; ++j){
        float c4 = (j <= 4) ? col[j][4] : NEGC;
        float c5 = (j <= 5) ? col[j][5] : NEGC;
        float c6 = col[j][6];
        float ce = (endsel == 0) ? c4 : ((endsel == 1) ? c5 : c6);
        uvec[j] = fmaxf(uvec[j], ce);
      }
      float be = (endsel == 0) ? bvec[4] : ((endsel == 1) ? bvec[5] : bvec[6]);
      w = fmaxf(w, be);
    }
  };

  unsigned qa[7], qb[7];
  {
    const unsigned* rp = (const unsigned*)(transB + (size_t)sdocs[0] * (MP*2) + p*28);
    #pragma unroll
    for (int i = 0; i < 7; ++i) qa[i] = rp[i];
  }
  int tbase = ch * CHUNK;
  for (int s = 0; s < CHUNK; s += 2){
    {
      const unsigned* rp = (const unsigned*)(transB + (size_t)sdocs[s+1] * (MP*2) + p*28);
      #pragma unroll
      for (int i = 0; i < 7; ++i) qb[i] = rp[i];
    }
    step(qa, (tbase + s) < doclen);
    if (s + 2 < CHUNK){
      const unsigned* rp = (const unsigned*)(transB + (size_t)sdocs[s+2] * (MP*2) + p*28);
      #pragma unroll
      for (int i = 0; i < 7; ++i) qa[i] = rp[i];
    }
    step(qb, (tbase + s + 1) < doclen);
  }

  float out[44];
  int idx = 0;
  #pragma unroll
  for (int j = 0; j < 7; ++j)
    #pragma unroll
    for (int l = j; l < 7; ++l) out[idx++] = col[j][l];
  #pragma unroll
  for (int l = 0; l < 7; ++l) out[28 + l] = bvec[l];
  #pragma unroll
  for (int l = 0; l < 7; ++l) out[35 + l] = uvec[l];
  out[42] = w; out[43] = 0.f;
  float* dst = chunkout + ((size_t)(b * NCH + ch) * P_ + p) * 44;
  #pragma unroll
  for (int i = 0; i < 11; ++i){
    float4 t2 = make_float4(out[4*i], out[4*i+1], out[4*i+2], out[4*i+3]);
    ((float4*)dst)[i] = t2;
  }
}

// ---------------- K45: per-(b,p) fold of 32 chunks + MLP head
__global__ __launch_bounds__(192) void k_combine_mlp(const float* __restrict__ chunkout,
                                                     const float* __restrict__ w0,
                                                     const float* __restrict__ b0,
                                                     const float* __restrict__ w1,
                                                     const float* __restrict__ b1,
                                                     float* __restrict__ out){
  __shared__ float ssc[P_];
  __shared__ float sh[100];
  int b = blockIdx.x, tid = threadIdx.x;
  if (tid < P_){
    int p = tid;
    float h[7] = {0.f, -100.f, -100.f, -100.f, -100.f, -100.f, -100.f};
    float sc = -100.f;
    for (int ch = 0; ch < NCH; ++ch){
      const float* rec = chunkout + ((size_t)(b * NCH + ch) * P_ + p) * 44;
      float r[44];
      #pragma unroll
      for (int i = 0; i < 11; ++i){
        float4 t = ((const float4*)rec)[i];
        r[4*i] = t.x; r[4*i+1] = t.y; r[4*i+2] = t.z; r[4*i+3] = t.w;
      }
      // score with OLD h (u . h, w)
      #pragma unroll
      for (int j = 0; j < 7; ++j) sc = fmaxf(sc, r[35 + j] + h[j]);
      sc = fmaxf(sc, r[42]);
      // h' = A (x) h  (+)  b
      constexpr int off[7] = {0, 7, 13, 18, 22, 25, 27};
      float nh[7];
      #pragma unroll
      for (int l = 0; l < 7; ++l){
        float v = r[28 + l];
        #pragma unroll
        for (int j = 0; j < 7; ++j){
          if (j <= l) v = fmaxf(v, r[off[j] + (l - j)] + h[j]);
        }
        nh[l] = v;
      }
      #pragma unroll
      for (int l = 0; l < 7; ++l) h[l] = nh[l];
    }
    ssc[p] = sc;
  }
  __syncthreads();
  if (tid < 100){
    float a = b0[tid];
    for (int pp = 0; pp < P_; ++pp) a += ssc[pp] * w0[pp * 100 + tid];
    sh[tid] = fmaxf(a, 0.f);
  }
  __syncthreads();
  if (tid < 2){
    float o = b1[tid];
    for (int j = 0; j < 100; ++j) o += sh[j] * w1[j * 2 + tid];
    out[b * 2 + tid] = o;
  }
}

extern "C" void kernel_launch(void* const* d_in, const int* in_sizes, int n_in,
                              void* d_out, int out_size, void* d_ws, size_t ws_size,
                              hipStream_t stream){
  const float* emb   = (const float*)d_in[0];   // [300][50000]
  const float* diags = (const float*)d_in[1];   // [2100][300]
  const float* bias  = (const float*)d_in[2];   // [2100]
  const float* eps   = (const float*)d_in[3];   // [150][6]
  const float* w0    = (const float*)d_in[4];   // [150][100]
  const float* b0    = (const float*)d_in[5];   // [100]
  const float* w1    = (const float*)d_in[6];   // [100][2]
  const float* b1    = (const float*)d_in[7];   // [2]
  const int* docs    = (const int*)d_in[8];     // [32][2048]
  const int* dlens   = (const int*)d_in[9];     // [32]

  if (ws_size < (size_t)WS_NEEDED) return;   // diagnostic: all-zero output => ws too small

  char* ws = (char*)d_ws;
  unsigned short* embT   = (unsigned short*)(ws + WS_EMBT);
  unsigned short* diagsB = (unsigned short*)(ws + WS_DIAGSB);
  unsigned short* trans  = (unsigned short*)(ws + WS_TRANS);
  float* chunkout        = (float*)(ws + WS_CHUNKOUT);   // aliases embT (dead after k_gemm)
  float* outp = (float*)d_out;

  k_transpose_emb<<<dim3(NPAD/32, KP/32), 256, 0, stream>>>(emb, embT);
  k_conv_diags<<<(MP*KP/4 + 255)/256, 256, 0, stream>>>(diags, diagsB);
  k_gemm<<<33 * (NPAD/128), 256, 0, stream>>>(embT, diagsB, bias, trans);
  k_scan<<<B_ * NCH, 192, 0, stream>>>(trans, docs, dlens, eps, chunkout);
  k_combine_mlp<<<B_, 192, 0, stream>>>(chunkout, w0, b0, w1, b1, outp);
}

// Round 3
// 256.200 us; speedup vs baseline: 1.2226x; 1.2226x over previous
//
#include <hip/hip_runtime.h>
#include <stdint.h>

#define B_   32
#define T_   2048
#define V_   50000
#define WD_  300
#define P_   150
#define KP   320      // K padded (300 -> 320)
#define MP   2112     // trans row stride in elements
#define MB2  2176     // diagsB padded rows (17 tiles of 128)
#define NPAD 50048    // V padded to 128-multiple
#define CHUNK 64
#define NCH   32
#define NEGC (-1.0e30f)
#define VT_  391      // NPAD/128
#define MT_  17
#define NWG  6647     // VT_*MT_

// workspace layout (bytes)
#define WS_EMBT      0u             // 50048*320*2 = 32,030,720 (reused as chunkout later)
#define WS_DIAGSB    32030720u      // 2176*320*2  =  1,392,640
#define WS_TRANS     33423360u      // 50000*2112*2 = 211,200,000
#define WS_CHUNKOUT  0u             // 32*32*150*44*4 = 27,033,600 (aliases embT; gemm done by then)
#define WS_NEEDED    244623360u

typedef __attribute__((ext_vector_type(8))) short bf16x8;
typedef __attribute__((ext_vector_type(4))) float f32x4;

#define GLOAD_LDS16(gp, lp) __builtin_amdgcn_global_load_lds( \
    (__attribute__((address_space(1))) void*)(gp), \
    (__attribute__((address_space(3))) void*)(lp), 16, 0, 0)

__device__ __forceinline__ unsigned short f2bf(float f){
  unsigned u = __builtin_bit_cast(unsigned, f);
  u = u + 0x7fffu + ((u >> 16) & 1u);   // RNE
  return (unsigned short)(u >> 16);
}
__device__ __forceinline__ float bf_lo(unsigned u){ return __builtin_bit_cast(float, u << 16); }
__device__ __forceinline__ float bf_hi(unsigned u){ return __builtin_bit_cast(float, u & 0xffff0000u); }

// ---------------- K0a: emb [300][50000] f32 -> embT bf16 [NPAD][KP] (transposed, zero-padded)
__global__ __launch_bounds__(256) void k_transpose_emb(const float* __restrict__ emb,
                                                       unsigned short* __restrict__ embT){
  __shared__ float tile[32][33];
  int v0 = blockIdx.x * 32, k0 = blockIdx.y * 32;
  int tid = threadIdx.x;
  int vv = tid & 31;
  #pragma unroll
  for (int it = 0; it < 4; ++it){
    int kk = (tid >> 5) + it * 8;
    int k = k0 + kk, v = v0 + vv;
    float val = 0.f;
    if (k < WD_ && v < V_) val = emb[(size_t)k * V_ + v];
    tile[kk][vv] = val;
  }
  __syncthreads();
  int vv2 = tid >> 3, kq = tid & 7;
  unsigned short a = f2bf(tile[kq*4+0][vv2]);
  unsigned short b = f2bf(tile[kq*4+1][vv2]);
  unsigned short c = f2bf(tile[kq*4+2][vv2]);
  unsigned short d = f2bf(tile[kq*4+3][vv2]);
  uint2 pk;
  pk.x = (unsigned)a | ((unsigned)b << 16);
  pk.y = (unsigned)c | ((unsigned)d << 16);
  *(uint2*)&embT[(size_t)(v0 + vv2) * KP + k0 + kq*4] = pk;
}

// ---------------- K0b: diags [2100][300] f32 -> bf16 [MB2][KP] zero-padded
__global__ __launch_bounds__(256) void k_conv_diags(const float* __restrict__ diags,
                                                    unsigned short* __restrict__ diagsB){
  int gid = blockIdx.x * 256 + threadIdx.x;   // 0 .. 2176*80-1
  int m = gid / 80;
  int k4 = (gid % 80) * 4;
  unsigned short e[4];
  #pragma unroll
  for (int i = 0; i < 4; ++i){
    int k = k4 + i;
    float v = (m < 2100 && k < WD_) ? diags[m * WD_ + k] : 0.f;
    e[i] = f2bf(v);
  }
  uint2 pk;
  pk.x = (unsigned)e[0] | ((unsigned)e[1] << 16);
  pk.y = (unsigned)e[2] | ((unsigned)e[3] << 16);
  *(uint2*)&diagsB[(size_t)m * KP + k4] = pk;
}

// ---------------- K1: trans[v][m] = sum_k embT[v][k]*diagsB[m][k] + bias[m], bf16 out
// m97-style: 128x128 tile, 4 waves (2v x 2m), BK=64, global_load_lds w=16,
// pre-swizzled source chunks (c ^ (row&7)) for conflict-free ds_read_b128.
__global__ __launch_bounds__(256) void k_gemm(const unsigned short* __restrict__ embT,
                                              const unsigned short* __restrict__ diagsB,
                                              const float* __restrict__ bias,
                                              unsigned short* __restrict__ trans){
  __shared__ char smem[33792];   // main: A 16K + B 16K; epilogue: bf16 [128][132]
  // XCD-bijective blockIdx swizzle (nwg = 6647 = 8*830 + 7), mt-inner
  int orig = blockIdx.x;
  int xcd = orig & 7, bidx = orig >> 3;
  int wg = (xcd < 7 ? xcd * 831 : 5817 + (xcd - 7) * 830) + bidx;
  int vt = wg / MT_, mt = wg - vt * MT_;
  int v0 = vt * 128, m0 = mt * 128;

  int tid = threadIdx.x;
  int w = tid >> 6, l = tid & 63;
  int wv = w & 1, wm = w >> 1;
  int lrow = l & 15, lq = l >> 4;
  int sub = l >> 3, c0 = l & 7;
  int cc = c0 ^ sub;              // swizzled global source chunk

  f32x4 acc[4][4];
  #pragma unroll
  for (int i = 0; i < 4; ++i)
    #pragma unroll
    for (int j = 0; j < 4; ++j)
      acc[i][j] = (f32x4){0.f, 0.f, 0.f, 0.f};

  for (int kt = 0; kt < 5; ++kt){
    int k0 = kt * 64;
    // stage A (128x64 bf16) + B (128x64 bf16): per wave 8 rows x 4 iters each
    #pragma unroll
    for (int i = 0; i < 4; ++i){
      int rbase = w * 32 + i * 8;
      GLOAD_LDS16(&embT[(size_t)(v0 + rbase + sub) * KP + k0 + cc * 8],
                  smem + rbase * 128);
      GLOAD_LDS16(&diagsB[(size_t)(m0 + rbase + sub) * KP + k0 + cc * 8],
                  smem + 16384 + rbase * 128);
    }
    __syncthreads();
    #pragma unroll
    for (int kk = 0; kk < 2; ++kk){
      bf16x8 af[4], bg[4];
      #pragma unroll
      for (int i = 0; i < 4; ++i){
        int row = wv * 64 + i * 16 + lrow;
        af[i] = *(const bf16x8*)(smem + row * 128 + (((kk << 2) | lq) ^ (row & 7)) * 16);
      }
      #pragma unroll
      for (int j = 0; j < 4; ++j){
        int row = wm * 64 + j * 16 + lrow;
        bg[j] = *(const bf16x8*)(smem + 16384 + row * 128 + (((kk << 2) | lq) ^ (row & 7)) * 16);
      }
      #pragma unroll
      for (int i = 0; i < 4; ++i)
        #pragma unroll
        for (int j = 0; j < 4; ++j)
          acc[i][j] = __builtin_amdgcn_mfma_f32_16x16x32_bf16(af[i], bg[j], acc[i][j], 0, 0, 0);
    }
    __syncthreads();
  }

  // bias per thread's 4 col-groups
  float bv4[4];
  #pragma unroll
  for (int j = 0; j < 4; ++j){
    int mg = m0 + wm * 64 + j * 16 + lrow;
    bv4[j] = (mg < 2100) ? bias[mg] : 0.f;
  }
  // epilogue: regs -> bf16 LDS [128][132] -> coalesced uint2 stores
  unsigned short* eb = (unsigned short*)smem;
  #pragma unroll
  for (int i = 0; i < 4; ++i)
    #pragma unroll
    for (int j = 0; j < 4; ++j)
      #pragma unroll
      for (int r = 0; r < 4; ++r){
        int row = wv * 64 + i * 16 + lq * 4 + r;
        int col = wm * 64 + j * 16 + lrow;
        eb[row * 132 + col] = f2bf(acc[i][j][r] + bv4[j]);
      }
  __syncthreads();
  #pragma unroll
  for (int it = 0; it < 16; ++it){
    int idx2 = it * 256 + tid;
    int row = idx2 >> 5, ch = idx2 & 31;   // ch: 8-byte units (4 bf16)
    int vg = v0 + row, mg = m0 + ch * 4;
    if (vg < V_ && mg < MP){
      uint2 val = *(const uint2*)(smem + row * 264 + ch * 8);
      *(uint2*)&trans[(size_t)vg * MP + mg] = val;
    }
  }
}

// ---------------- K3: chunked affine max-plus scan
// per (b, chunk, p): fold 64 steps into (A cols tri-28, b 7, u 7, w 1) -> chunkout[...][44]
__global__ __launch_bounds__(192) void k_scan(const unsigned short* __restrict__ trans,
                                              const int* __restrict__ docs,
                                              const int* __restrict__ doc_lens,
                                              const float* __restrict__ epsilon,
                                              float* __restrict__ chunkout){
  __shared__ int sdocs[CHUNK];
  int b = blockIdx.x >> 5, ch = blockIdx.x & 31;
  int tid = threadIdx.x;
  if (tid < CHUNK) sdocs[tid] = docs[b * T_ + ch * CHUNK + tid];
  __syncthreads();
  int p = tid;
  if (p >= P_) return;
  int doclen = doc_lens[b];
  float eps_r[6];
  #pragma unroll
  for (int i = 0; i < 6; ++i) eps_r[i] = epsilon[p*6 + i];
  int endsel = p / 50;   // 0,1,2 -> end state 4,5,6

  float col[7][7], bvec[7], uvec[7], w;
  #pragma unroll
  for (int j = 0; j < 7; ++j)
    #pragma unroll
    for (int l = 0; l < 7; ++l) col[j][l] = (j == l) ? 0.f : NEGC;
  #pragma unroll
  for (int l = 0; l < 7; ++l){ bvec[l] = NEGC; uvec[l] = NEGC; }
  w = NEGC;

  const char* transB = (const char*)trans;

  auto step = [&](const unsigned* q, bool act){
    float tsf[7], tmn[6];
    tsf[0]=bf_lo(q[0]); tsf[1]=bf_hi(q[0]);
    tsf[2]=bf_lo(q[1]); tsf[3]=bf_hi(q[1]);
    tsf[4]=bf_lo(q[2]); tsf[5]=bf_hi(q[2]);
    tsf[6]=bf_lo(q[3]); tmn[0]=bf_hi(q[3]);
    tmn[1]=bf_lo(q[4]); tmn[2]=bf_hi(q[4]);
    tmn[3]=bf_lo(q[5]); tmn[4]=bf_hi(q[5]);
    tmn[5]=bf_lo(q[6]);
    // linear part: update each (triangular) column, descending l so old values are read
    #pragma unroll
    for (int j = 0; j < 7; ++j){
      #pragma unroll
      for (int l = 6; l >= 1; --l){
        if (l < j) continue;
        if (l == j){ col[j][l] = col[j][l] + tsf[l]; continue; }
        float ae;
        if (l - 1 == j) ae = col[j][l-1];
        else ae = fmaxf(col[j][l-1], col[j][l-2] + eps_r[l-2]);
        col[j][l] = fmaxf(ae + tmn[l-1], col[j][l] + tsf[l]);
      }
      if (j == 0) col[0][0] += tsf[0];
    }
    // const part: full reference map incl. restart(0) and zero_pad(-100)
    #pragma unroll
    for (int l = 6; l >= 1; --l){
      float ae;
      if (l == 1) ae = fmaxf(bvec[0], -100.0f);
      else ae = fmaxf(bvec[l-1], bvec[l-2] + eps_r[l-2]);
      bvec[l] = fmaxf(ae + tmn[l-1], bvec[l] + tsf[l]);
    }
    bvec[0] = fmaxf(0.0f, bvec[0] + tsf[0]);
    if (act){
      #pragma unroll
      for (int j = 0; j < 7; ++j){
        float c4 = (j <= 4) ? col[j][4] : NEGC;
        float c5 = (j <= 5) ? col[j][5] : NEGC;
        float c6 = col[j][6];
        float ce = (endsel == 0) ? c4 : ((endsel == 1) ? c5 : c6);
        uvec[j] = fmaxf(uvec[j], ce);
      }
      float be = (endsel == 0) ? bvec[4] : ((endsel == 1) ? bvec[5] : bvec[6]);
      w = fmaxf(w, be);
    }
  };

  unsigned qa[7], qb[7];
  {
    const unsigned* rp = (const unsigned*)(transB + (size_t)sdocs[0] * (MP*2) + p*28);
    #pragma unroll
    for (int i = 0; i < 7; ++i) qa[i] = rp[i];
  }
  int tbase = ch * CHUNK;
  for (int s = 0; s < CHUNK; s += 2){
    {
      const unsigned* rp = (const unsigned*)(transB + (size_t)sdocs[s+1] * (MP*2) + p*28);
      #pragma unroll
      for (int i = 0; i < 7; ++i) qb[i] = rp[i];
    }
    step(qa, (tbase + s) < doclen);
    if (s + 2 < CHUNK){
      const unsigned* rp = (const unsigned*)(transB + (size_t)sdocs[s+2] * (MP*2) + p*28);
      #pragma unroll
      for (int i = 0; i < 7; ++i) qa[i] = rp[i];
    }
    step(qb, (tbase + s + 1) < doclen);
  }

  float out[44];
  int idx = 0;
  #pragma unroll
  for (int j = 0; j < 7; ++j)
    #pragma unroll
    for (int l = j; l < 7; ++l) out[idx++] = col[j][l];
  #pragma unroll
  for (int l = 0; l < 7; ++l) out[28 + l] = bvec[l];
  #pragma unroll
  for (int l = 0; l < 7; ++l) out[35 + l] = uvec[l];
  out[42] = w; out[43] = 0.f;
  float* dst = chunkout + ((size_t)(b * NCH + ch) * P_ + p) * 44;
  #pragma unroll
  for (int i = 0; i < 11; ++i){
    float4 t2 = make_float4(out[4*i], out[4*i+1], out[4*i+2], out[4*i+3]);
    ((float4*)dst)[i] = t2;
  }
}

// ---------------- K45: per-(b,p) fold of 32 chunks + MLP head
__global__ __launch_bounds__(192) void k_combine_mlp(const float* __restrict__ chunkout,
                                                     const float* __restrict__ w0,
                                                     const float* __restrict__ b0,
                                                     const float* __restrict__ w1,
                                                     const float* __restrict__ b1,
                                                     float* __restrict__ out){
  __shared__ float ssc[P_];
  __shared__ float sh[100];
  int b = blockIdx.x, tid = threadIdx.x;
  if (tid < P_){
    int p = tid;
    float h[7] = {0.f, -100.f, -100.f, -100.f, -100.f, -100.f, -100.f};
    float sc = -100.f;
    for (int ch = 0; ch < NCH; ++ch){
      const float* rec = chunkout + ((size_t)(b * NCH + ch) * P_ + p) * 44;
      float r[44];
      #pragma unroll
      for (int i = 0; i < 11; ++i){
        float4 t = ((const float4*)rec)[i];
        r[4*i] = t.x; r[4*i+1] = t.y; r[4*i+2] = t.z; r[4*i+3] = t.w;
      }
      // score with OLD h (u . h, w)
      #pragma unroll
      for (int j = 0; j < 7; ++j) sc = fmaxf(sc, r[35 + j] + h[j]);
      sc = fmaxf(sc, r[42]);
      // h' = A (x) h  (+)  b
      constexpr int off[7] = {0, 7, 13, 18, 22, 25, 27};
      float nh[7];
      #pragma unroll
      for (int l = 0; l < 7; ++l){
        float v = r[28 + l];
        #pragma unroll
        for (int j = 0; j < 7; ++j){
          if (j <= l) v = fmaxf(v, r[off[j] + (l - j)] + h[j]);
        }
        nh[l] = v;
      }
      #pragma unroll
      for (int l = 0; l < 7; ++l) h[l] = nh[l];
    }
    ssc[p] = sc;
  }
  __syncthreads();
  if (tid < 100){
    float a = b0[tid];
    for (int pp = 0; pp < P_; ++pp) a += ssc[pp] * w0[pp * 100 + tid];
    sh[tid] = fmaxf(a, 0.f);
  }
  __syncthreads();
  if (tid < 2){
    float o = b1[tid];
    for (int j = 0; j < 100; ++j) o += sh[j] * w1[j * 2 + tid];
    out[b * 2 + tid] = o;
  }
}

extern "C" void kernel_launch(void* const* d_in, const int* in_sizes, int n_in,
                              void* d_out, int out_size, void* d_ws, size_t ws_size,
                              hipStream_t stream){
  const float* emb   = (const float*)d_in[0];   // [300][50000]
  const float* diags = (const float*)d_in[1];   // [2100][300]
  const float* bias  = (const float*)d_in[2];   // [2100]
  const float* eps   = (const float*)d_in[3];   // [150][6]
  const float* w0    = (const float*)d_in[4];   // [150][100]
  const float* b0    = (const float*)d_in[5];   // [100]
  const float* w1    = (const float*)d_in[6];   // [100][2]
  const float* b1    = (const float*)d_in[7];   // [2]
  const int* docs    = (const int*)d_in[8];     // [32][2048]
  const int* dlens   = (const int*)d_in[9];     // [32]

  if (ws_size < (size_t)WS_NEEDED) return;   // diagnostic: all-zero output => ws too small

  char* ws = (char*)d_ws;
  unsigned short* embT   = (unsigned short*)(ws + WS_EMBT);
  unsigned short* diagsB = (unsigned short*)(ws + WS_DIAGSB);
  unsigned short* trans  = (unsigned short*)(ws + WS_TRANS);
  float* chunkout        = (float*)(ws + WS_CHUNKOUT);   // aliases embT (dead after k_gemm)
  float* outp = (float*)d_out;

  k_transpose_emb<<<dim3(NPAD/32, KP/32), 256, 0, stream>>>(emb, embT);
  k_conv_diags<<<(MB2*80 + 255)/256, 256, 0, stream>>>(diags, diagsB);
  k_gemm<<<NWG, 256, 0, stream>>>(embT, diagsB, bias, trans);
  k_scan<<<B_ * NCH, 192, 0, stream>>>(trans, docs, dlens, eps, chunkout);
  k_combine_mlp<<<B_, 192, 0, stream>>>(chunkout, w0, b0, w1, b1, outp);
}

// Round 4
// 239.596 us; speedup vs baseline: 1.3073x; 1.0693x over previous
//
#include <hip/hip_runtime.h>
#include <stdint.h>

#define B_   32
#define T_   2048
#define V_   50000
#define WD_  300
#define P_   150
#define KP   320      // K padded (300 -> 320)
#define MP   2112     // trans row stride in elements
#define MB2  2176     // diagsB padded rows (17 tiles of 128)
#define NPAD 50048    // V padded to 128-multiple
#define CHUNK 64
#define NCH   32
#define NEGC (-1.0e30f)
#define VT_  391      // NPAD/128
#define MT_  17
#define NWG  6647     // VT_*MT_

// workspace layout (bytes)
#define WS_EMBT      0u             // 50048*320*2 = 32,030,720 (reused as chunkout later)
#define WS_DIAGSB    32030720u      // 2176*320*2  =  1,392,640
#define WS_TRANS     33423360u      // 50000*2112*2 = 211,200,000
#define WS_CHUNKOUT  0u             // 32*32*150*44*4 = 27,033,600 (aliases embT; gemm done by then)
#define WS_NEEDED    244623360u

typedef __attribute__((ext_vector_type(8))) short bf16x8;
typedef __attribute__((ext_vector_type(4))) float f32x4;

#define GLOAD_LDS16(gp, lp) __builtin_amdgcn_global_load_lds( \
    (__attribute__((address_space(1))) void*)(gp), \
    (__attribute__((address_space(3))) void*)(lp), 16, 0, 0)

__device__ __forceinline__ unsigned short f2bf(float f){
  unsigned u = __builtin_bit_cast(unsigned, f);
  u = u + 0x7fffu + ((u >> 16) & 1u);   // RNE
  return (unsigned short)(u >> 16);
}
__device__ __forceinline__ float bf_lo(unsigned u){ return __builtin_bit_cast(float, u << 16); }
__device__ __forceinline__ float bf_hi(unsigned u){ return __builtin_bit_cast(float, u & 0xffff0000u); }

// ---------------- K0a: emb [300][50000] f32 -> embT bf16 [NPAD][KP] (transposed, zero-padded)
__global__ __launch_bounds__(256) void k_transpose_emb(const float* __restrict__ emb,
                                                       unsigned short* __restrict__ embT){
  __shared__ float tile[32][33];
  int v0 = blockIdx.x * 32, k0 = blockIdx.y * 32;
  int tid = threadIdx.x;
  int vv = tid & 31;
  #pragma unroll
  for (int it = 0; it < 4; ++it){
    int kk = (tid >> 5) + it * 8;
    int k = k0 + kk, v = v0 + vv;
    float val = 0.f;
    if (k < WD_ && v < V_) val = emb[(size_t)k * V_ + v];
    tile[kk][vv] = val;
  }
  __syncthreads();
  int vv2 = tid >> 3, kq = tid & 7;
  unsigned short a = f2bf(tile[kq*4+0][vv2]);
  unsigned short b = f2bf(tile[kq*4+1][vv2]);
  unsigned short c = f2bf(tile[kq*4+2][vv2]);
  unsigned short d = f2bf(tile[kq*4+3][vv2]);
  uint2 pk;
  pk.x = (unsigned)a | ((unsigned)b << 16);
  pk.y = (unsigned)c | ((unsigned)d << 16);
  *(uint2*)&embT[(size_t)(v0 + vv2) * KP + k0 + kq*4] = pk;
}

// ---------------- K0b: diags [2100][300] f32 -> bf16 [MB2][KP] zero-padded
__global__ __launch_bounds__(256) void k_conv_diags(const float* __restrict__ diags,
                                                    unsigned short* __restrict__ diagsB){
  int gid = blockIdx.x * 256 + threadIdx.x;   // 0 .. 2176*80-1
  int m = gid / 80;
  int k4 = (gid % 80) * 4;
  unsigned short e[4];
  #pragma unroll
  for (int i = 0; i < 4; ++i){
    int k = k4 + i;
    float v = (m < 2100 && k < WD_) ? diags[m * WD_ + k] : 0.f;
    e[i] = f2bf(v);
  }
  uint2 pk;
  pk.x = (unsigned)e[0] | ((unsigned)e[1] << 16);
  pk.y = (unsigned)e[2] | ((unsigned)e[3] << 16);
  *(uint2*)&diagsB[(size_t)m * KP + k4] = pk;
}

// ---------------- K1: trans[v][m] = sum_k embT[v][k]*diagsB[m][k] + bias[m], bf16 out
// 128x128 tile, 4 waves, BK=64, double-buffered LDS, counted vmcnt (2-phase T3/T4),
// pre-swizzled global source chunks (c ^ (row&7)) for conflict-free ds_read_b128.
__global__ __launch_bounds__(256) void k_gemm(const unsigned short* __restrict__ embT,
                                              const unsigned short* __restrict__ diagsB,
                                              const float* __restrict__ bias,
                                              unsigned short* __restrict__ trans){
  __shared__ char smem[65536];   // 2 x (A 16K + B 16K); epilogue reuses first 33792 B
  // XCD-bijective blockIdx swizzle (nwg = 6647 = 8*830 + 7), mt-inner
  int orig = blockIdx.x;
  int xcd = orig & 7, bidx = orig >> 3;
  int wg = (xcd < 7 ? xcd * 831 : 5817 + (xcd - 7) * 830) + bidx;
  int vt = wg / MT_, mt = wg - vt * MT_;
  int v0 = vt * 128, m0 = mt * 128;

  int tid = threadIdx.x;
  int w = tid >> 6, l = tid & 63;
  int wv = w & 1, wm = w >> 1;
  int lrow = l & 15, lq = l >> 4;
  int sub = l >> 3, c0 = l & 7;
  int cc = c0 ^ sub;              // swizzled global source chunk

  f32x4 acc[4][4];
  #pragma unroll
  for (int i = 0; i < 4; ++i)
    #pragma unroll
    for (int j = 0; j < 4; ++j)
      acc[i][j] = (f32x4){0.f, 0.f, 0.f, 0.f};

  auto STAGE = [&](int buf, int kt){
    int k0 = kt * 64;
    char* bA = smem + buf * 32768;
    char* bB = bA + 16384;
    #pragma unroll
    for (int i = 0; i < 4; ++i){
      int rbase = w * 32 + i * 8;
      GLOAD_LDS16(&embT[(size_t)(v0 + rbase + sub) * KP + k0 + cc * 8], bA + rbase * 128);
      GLOAD_LDS16(&diagsB[(size_t)(m0 + rbase + sub) * KP + k0 + cc * 8], bB + rbase * 128);
    }
  };

  STAGE(0, 0);
  #pragma unroll
  for (int kt = 0; kt < 5; ++kt){
    if (kt < 4) STAGE((kt + 1) & 1, kt + 1);
    if (kt < 4) asm volatile("s_waitcnt vmcnt(8)" ::: "memory");
    else        asm volatile("s_waitcnt vmcnt(0)" ::: "memory");
    __builtin_amdgcn_s_barrier();
    __builtin_amdgcn_sched_barrier(0);
    char* bA = smem + (kt & 1) * 32768;
    char* bB = bA + 16384;
    #pragma unroll
    for (int kk = 0; kk < 2; ++kk){
      bf16x8 af[4], bg[4];
      #pragma unroll
      for (int i = 0; i < 4; ++i){
        int row = wv * 64 + i * 16 + lrow;
        af[i] = *(const bf16x8*)(bA + row * 128 + (((kk << 2) | lq) ^ (row & 7)) * 16);
      }
      #pragma unroll
      for (int j = 0; j < 4; ++j){
        int row = wm * 64 + j * 16 + lrow;
        bg[j] = *(const bf16x8*)(bB + row * 128 + (((kk << 2) | lq) ^ (row & 7)) * 16);
      }
      #pragma unroll
      for (int i = 0; i < 4; ++i)
        #pragma unroll
        for (int j = 0; j < 4; ++j)
          acc[i][j] = __builtin_amdgcn_mfma_f32_16x16x32_bf16(af[i], bg[j], acc[i][j], 0, 0, 0);
    }
    __builtin_amdgcn_sched_barrier(0);
    __builtin_amdgcn_s_barrier();
  }

  // bias per thread's 4 col-groups
  float bv4[4];
  #pragma unroll
  for (int j = 0; j < 4; ++j){
    int mg = m0 + wm * 64 + j * 16 + lrow;
    bv4[j] = (mg < 2100) ? bias[mg] : 0.f;
  }
  // epilogue: regs -> bf16 LDS [128][132] -> coalesced uint2 stores
  unsigned short* eb = (unsigned short*)smem;
  #pragma unroll
  for (int i = 0; i < 4; ++i)
    #pragma unroll
    for (int j = 0; j < 4; ++j)
      #pragma unroll
      for (int r = 0; r < 4; ++r){
        int row = wv * 64 + i * 16 + lq * 4 + r;
        int col = wm * 64 + j * 16 + lrow;
        eb[row * 132 + col] = f2bf(acc[i][j][r] + bv4[j]);
      }
  __syncthreads();
  #pragma unroll
  for (int it = 0; it < 16; ++it){
    int idx2 = it * 256 + tid;
    int row = idx2 >> 5, ch = idx2 & 31;   // ch: 8-byte units (4 bf16)
    int vg = v0 + row, mg = m0 + ch * 4;
    if (vg < V_ && mg < MP){
      uint2 val = *(const uint2*)(smem + row * 264 + ch * 8);
      *(uint2*)&trans[(size_t)vg * MP + mg] = val;
    }
  }
}

// ---------------- K3: chunked affine max-plus scan
// per (b, chunk, p): fold 64 steps into (A cols tri-28, b 7, u 7, w 1) -> chunkout[...][44]
// distance-3 software-pipelined prefetch with named register sets (no runtime indexing)
__global__ __launch_bounds__(192) void k_scan(const unsigned short* __restrict__ trans,
                                              const int* __restrict__ docs,
                                              const int* __restrict__ doc_lens,
                                              const float* __restrict__ epsilon,
                                              float* __restrict__ chunkout){
  __shared__ int sdocs[CHUNK];
  int b = blockIdx.x >> 5, ch = blockIdx.x & 31;
  int tid = threadIdx.x;
  if (tid < CHUNK) sdocs[tid] = docs[b * T_ + ch * CHUNK + tid];
  __syncthreads();
  int p = tid;
  if (p >= P_) return;
  int doclen = doc_lens[b];
  float eps_r[6];
  #pragma unroll
  for (int i = 0; i < 6; ++i) eps_r[i] = epsilon[p*6 + i];
  int endsel = p / 50;   // 0,1,2 -> end state 4,5,6

  float col[7][7], bvec[7], uvec[7], w;
  #pragma unroll
  for (int j = 0; j < 7; ++j)
    #pragma unroll
    for (int l = 0; l < 7; ++l) col[j][l] = (j == l) ? 0.f : NEGC;
  #pragma unroll
  for (int l = 0; l < 7; ++l){ bvec[l] = NEGC; uvec[l] = NEGC; }
  w = NEGC;

  const char* transB = (const char*)trans;

  auto LOADQ = [&](unsigned* q, int s){
    int idx = s < 63 ? s : 63;
    const unsigned* rp = (const unsigned*)(transB + (size_t)sdocs[idx] * (MP*2) + p*28);
    #pragma unroll
    for (int i = 0; i < 7; ++i) q[i] = rp[i];
  };

  auto step = [&](const unsigned* q, bool act){
    float tsf[7], tmn[6];
    tsf[0]=bf_lo(q[0]); tsf[1]=bf_hi(q[0]);
    tsf[2]=bf_lo(q[1]); tsf[3]=bf_hi(q[1]);
    tsf[4]=bf_lo(q[2]); tsf[5]=bf_hi(q[2]);
    tsf[6]=bf_lo(q[3]); tmn[0]=bf_hi(q[3]);
    tmn[1]=bf_lo(q[4]); tmn[2]=bf_hi(q[4]);
    tmn[3]=bf_lo(q[5]); tmn[4]=bf_hi(q[5]);
    tmn[5]=bf_lo(q[6]);
    // linear part: update each (triangular) column, descending l so old values are read
    #pragma unroll
    for (int j = 0; j < 7; ++j){
      #pragma unroll
      for (int l = 6; l >= 1; --l){
        if (l < j) continue;
        if (l == j){ col[j][l] = col[j][l] + tsf[l]; continue; }
        float ae;
        if (l - 1 == j) ae = col[j][l-1];
        else ae = fmaxf(col[j][l-1], col[j][l-2] + eps_r[l-2]);
        col[j][l] = fmaxf(ae + tmn[l-1], col[j][l] + tsf[l]);
      }
      if (j == 0) col[0][0] += tsf[0];
    }
    // const part: full reference map incl. restart(0) and zero_pad(-100)
    #pragma unroll
    for (int l = 6; l >= 1; --l){
      float ae;
      if (l == 1) ae = fmaxf(bvec[0], -100.0f);
      else ae = fmaxf(bvec[l-1], bvec[l-2] + eps_r[l-2]);
      bvec[l] = fmaxf(ae + tmn[l-1], bvec[l] + tsf[l]);
    }
    bvec[0] = fmaxf(0.0f, bvec[0] + tsf[0]);
    if (act){
      #pragma unroll
      for (int j = 0; j < 7; ++j){
        float c4 = (j <= 4) ? col[j][4] : NEGC;
        float c5 = (j <= 5) ? col[j][5] : NEGC;
        float c6 = col[j][6];
        float ce = (endsel == 0) ? c4 : ((endsel == 1) ? c5 : c6);
        uvec[j] = fmaxf(uvec[j], ce);
      }
      float be = (endsel == 0) ? bvec[4] : ((endsel == 1) ? bvec[5] : bvec[6]);
      w = fmaxf(w, be);
    }
  };

  unsigned q0[7], q1[7], q2[7], q3[7];
  LOADQ(q0, 0); LOADQ(q1, 1); LOADQ(q2, 2);
  int tbase = ch * CHUNK;
  for (int s = 0; s < CHUNK; s += 4){
    LOADQ(q3, s + 3); step(q0, (tbase + s)     < doclen);
    LOADQ(q0, s + 4); step(q1, (tbase + s + 1) < doclen);
    LOADQ(q1, s + 5); step(q2, (tbase + s + 2) < doclen);
    LOADQ(q2, s + 6); step(q3, (tbase + s + 3) < doclen);
  }

  float out[44];
  int idx = 0;
  #pragma unroll
  for (int j = 0; j < 7; ++j)
    #pragma unroll
    for (int l = j; l < 7; ++l) out[idx++] = col[j][l];
  #pragma unroll
  for (int l = 0; l < 7; ++l) out[28 + l] = bvec[l];
  #pragma unroll
  for (int l = 0; l < 7; ++l) out[35 + l] = uvec[l];
  out[42] = w; out[43] = 0.f;
  float* dst = chunkout + ((size_t)(b * NCH + ch) * P_ + p) * 44;
  #pragma unroll
  for (int i = 0; i < 11; ++i){
    float4 t2 = make_float4(out[4*i], out[4*i+1], out[4*i+2], out[4*i+3]);
    ((float4*)dst)[i] = t2;
  }
}

// ---------------- K45: per-(b,p) fold of 32 chunks + MLP head
__global__ __launch_bounds__(192) void k_combine_mlp(const float* __restrict__ chunkout,
                                                     const float* __restrict__ w0,
                                                     const float* __restrict__ b0,
                                                     const float* __restrict__ w1,
                                                     const float* __restrict__ b1,
                                                     float* __restrict__ out){
  __shared__ float ssc[P_];
  __shared__ float sh[100];
  int b = blockIdx.x, tid = threadIdx.x;
  if (tid < P_){
    int p = tid;
    float h[7] = {0.f, -100.f, -100.f, -100.f, -100.f, -100.f, -100.f};
    float sc = -100.f;
    for (int ch = 0; ch < NCH; ++ch){
      const float* rec = chunkout + ((size_t)(b * NCH + ch) * P_ + p) * 44;
      float r[44];
      #pragma unroll
      for (int i = 0; i < 11; ++i){
        float4 t = ((const float4*)rec)[i];
        r[4*i] = t.x; r[4*i+1] = t.y; r[4*i+2] = t.z; r[4*i+3] = t.w;
      }
      // score with OLD h (u . h, w)
      #pragma unroll
      for (int j = 0; j < 7; ++j) sc = fmaxf(sc, r[35 + j] + h[j]);
      sc = fmaxf(sc, r[42]);
      // h' = A (x) h  (+)  b
      constexpr int off[7] = {0, 7, 13, 18, 22, 25, 27};
      float nh[7];
      #pragma unroll
      for (int l = 0; l < 7; ++l){
        float v = r[28 + l];
        #pragma unroll
        for (int j = 0; j < 7; ++j){
          if (j <= l) v = fmaxf(v, r[off[j] + (l - j)] + h[j]);
        }
        nh[l] = v;
      }
      #pragma unroll
      for (int l = 0; l < 7; ++l) h[l] = nh[l];
    }
    ssc[p] = sc;
  }
  __syncthreads();
  if (tid < 100){
    float a = b0[tid];
    for (int pp = 0; pp < P_; ++pp) a += ssc[pp] * w0[pp * 100 + tid];
    sh[tid] = fmaxf(a, 0.f);
  }
  __syncthreads();
  if (tid < 2){
    float o = b1[tid];
    for (int j = 0; j < 100; ++j) o += sh[j] * w1[j * 2 + tid];
    out[b * 2 + tid] = o;
  }
}

extern "C" void kernel_launch(void* const* d_in, const int* in_sizes, int n_in,
                              void* d_out, int out_size, void* d_ws, size_t ws_size,
                              hipStream_t stream){
  const float* emb   = (const float*)d_in[0];   // [300][50000]
  const float* diags = (const float*)d_in[1];   // [2100][300]
  const float* bias  = (const float*)d_in[2];   // [2100]
  const float* eps   = (const float*)d_in[3];   // [150][6]
  const float* w0    = (const float*)d_in[4];   // [150][100]
  const float* b0    = (const float*)d_in[5];   // [100]
  const float* w1    = (const float*)d_in[6];   // [100][2]
  const float* b1    = (const float*)d_in[7];   // [2]
  const int* docs    = (const int*)d_in[8];     // [32][2048]
  const int* dlens   = (const int*)d_in[9];     // [32]

  if (ws_size < (size_t)WS_NEEDED) return;   // diagnostic: all-zero output => ws too small

  char* ws = (char*)d_ws;
  unsigned short* embT   = (unsigned short*)(ws + WS_EMBT);
  unsigned short* diagsB = (unsigned short*)(ws + WS_DIAGSB);
  unsigned short* trans  = (unsigned short*)(ws + WS_TRANS);
  float* chunkout        = (float*)(ws + WS_CHUNKOUT);   // aliases embT (dead after k_gemm)
  float* outp = (float*)d_out;

  k_transpose_emb<<<dim3(NPAD/32, KP/32), 256, 0, stream>>>(emb, embT);
  k_conv_diags<<<(MB2*80 + 255)/256, 256, 0, stream>>>(diags, diagsB);
  k_gemm<<<NWG, 256, 0, stream>>>(embT, diagsB, bias, trans);
  k_scan<<<B_ * NCH, 192, 0, stream>>>(trans, docs, dlens, eps, chunkout);
  k_combine_mlp<<<B_, 192, 0, stream>>>(chunkout, w0, b0, w1, b1, outp);
}

// Round 5
// 220.681 us; speedup vs baseline: 1.4194x; 1.0857x over previous
//
#include <hip/hip_runtime.h>
#include <stdint.h>

#define B_   32
#define T_   2048
#define V_   50000
#define WD_  300
#define P_   150
#define KP   320      // K padded (300 -> 320)
#define MP   2112     // trans row stride in elements
#define MB2  2176     // diagsB padded rows (17 tiles of 128)
#define NPAD 50048    // V padded to 128-multiple
#define CHUNK 64
#define NCH   32
#define NEGC (-1.0e30f)
#define VT_  391      // NPAD/128
#define MT_  17
#define NWG  6647     // VT_*MT_

// workspace layout (bytes)
#define WS_EMBT      0u             // 50048*320*2 = 32,030,720 (reused as chunkout later)
#define WS_DIAGSB    32030720u      // 2176*320*2  =  1,392,640
#define WS_TRANS     33423360u      // 50000*2112*2 = 211,200,000
#define WS_CHUNKOUT  0u             // 32*32*150*44*4 = 27,033,600 (aliases embT; gemm done by then)
#define WS_NEEDED    244623360u

typedef __attribute__((ext_vector_type(8))) short bf16x8;
typedef __attribute__((ext_vector_type(4))) float f32x4;

#define GLOAD_LDS16(gp, lp) __builtin_amdgcn_global_load_lds( \
    (__attribute__((address_space(1))) void*)(gp), \
    (__attribute__((address_space(3))) void*)(lp), 16, 0, 0)

__device__ __forceinline__ unsigned short f2bf(float f){
  unsigned u = __builtin_bit_cast(unsigned, f);
  u = u + 0x7fffu + ((u >> 16) & 1u);   // RNE
  return (unsigned short)(u >> 16);
}
__device__ __forceinline__ float bf_lo(unsigned u){ return __builtin_bit_cast(float, u << 16); }
__device__ __forceinline__ float bf_hi(unsigned u){ return __builtin_bit_cast(float, u & 0xffff0000u); }

// ---------------- K0a: emb [300][50000] f32 -> embT bf16 [NPAD][KP] (transposed, zero-padded)
// 64(v) x 32(k) tiles; uint4 (16B) coalesced output stores
__global__ __launch_bounds__(256) void k_transpose_emb(const float* __restrict__ emb,
                                                       unsigned short* __restrict__ embT){
  __shared__ float tile[32][65];
  int v0 = blockIdx.x * 64, k0 = blockIdx.y * 32;
  int tid = threadIdx.x;
  #pragma unroll
  for (int it = 0; it < 8; ++it){
    int idx = it * 256 + tid;
    int kk = idx >> 6, vv = idx & 63;
    int k = k0 + kk, v = v0 + vv;
    float val = 0.f;
    if (k < WD_ && v < V_) val = emb[(size_t)k * V_ + v];
    tile[kk][vv] = val;
  }
  __syncthreads();
  int row = tid >> 2, c = tid & 3;     // row: v within tile, c: k-quad (8 bf16)
  unsigned short e[8];
  #pragma unroll
  for (int i = 0; i < 8; ++i) e[i] = f2bf(tile[c*8 + i][row]);
  uint4 pk;
  pk.x = (unsigned)e[0] | ((unsigned)e[1] << 16);
  pk.y = (unsigned)e[2] | ((unsigned)e[3] << 16);
  pk.z = (unsigned)e[4] | ((unsigned)e[5] << 16);
  pk.w = (unsigned)e[6] | ((unsigned)e[7] << 16);
  *(uint4*)&embT[(size_t)(v0 + row) * KP + k0 + c*8] = pk;
}

// ---------------- K0b: diags [2100][300] f32 -> bf16 [MB2][KP] zero-padded
__global__ __launch_bounds__(256) void k_conv_diags(const float* __restrict__ diags,
                                                    unsigned short* __restrict__ diagsB){
  int gid = blockIdx.x * 256 + threadIdx.x;   // 0 .. 2176*80-1
  int m = gid / 80;
  int k4 = (gid % 80) * 4;
  unsigned short e[4];
  #pragma unroll
  for (int i = 0; i < 4; ++i){
    int k = k4 + i;
    float v = (m < 2100 && k < WD_) ? diags[m * WD_ + k] : 0.f;
    e[i] = f2bf(v);
  }
  uint2 pk;
  pk.x = (unsigned)e[0] | ((unsigned)e[1] << 16);
  pk.y = (unsigned)e[2] | ((unsigned)e[3] << 16);
  *(uint2*)&diagsB[(size_t)m * KP + k4] = pk;
}

// ---------------- K1: trans[v][m] = sum_k embT[v][k]*diagsB[m][k] + bias[m], bf16 out
// 128x128 tile, 4 waves, BK=32, double-buffered LDS (33.8KB -> 4 blocks/CU),
// counted vmcnt(4), pre-swizzled source slot (lq ^ ((row>>1)&3)).
__global__ __launch_bounds__(256, 4) void k_gemm(const unsigned short* __restrict__ embT,
                                                 const unsigned short* __restrict__ diagsB,
                                                 const float* __restrict__ bias,
                                                 unsigned short* __restrict__ trans){
  __shared__ char smem[33792];   // 2 x (A 8K + B 8K) = 32K; epilogue bf16 [128][132] = 33792
  // XCD-bijective blockIdx swizzle (nwg = 6647 = 8*830 + 7), mt-inner
  int orig = blockIdx.x;
  int xcd = orig & 7, bidx = orig >> 3;
  int wg = (xcd < 7 ? xcd * 831 : 5817 + (xcd - 7) * 830) + bidx;
  int vt = wg / MT_, mt = wg - vt * MT_;
  int v0 = vt * 128, m0 = mt * 128;

  int tid = threadIdx.x;
  int w = tid >> 6, l = tid & 63;
  int wv = w & 1, wm = w >> 1;
  int lrow = l & 15, lq = l >> 4;

  f32x4 acc[4][4];
  #pragma unroll
  for (int i = 0; i < 4; ++i)
    #pragma unroll
    for (int j = 0; j < 4; ++j)
      acc[i][j] = (f32x4){0.f, 0.f, 0.f, 0.f};

  auto STAGE = [&](int buf, int kt){
    int k0 = kt * 32;
    char* bA = smem + buf * 16384;
    char* bB = bA + 8192;
    #pragma unroll
    for (int it = 0; it < 2; ++it){
      int idx = it * 256 + tid;
      int row = idx >> 2, slot = idx & 3;
      int sc = slot ^ ((row >> 1) & 3);   // pre-swizzled global chunk
      GLOAD_LDS16(&embT[(size_t)(v0 + row) * KP + k0 + sc * 8], bA + idx * 16);
      GLOAD_LDS16(&diagsB[(size_t)(m0 + row) * KP + k0 + sc * 8], bB + idx * 16);
    }
  };

  STAGE(0, 0);
  #pragma unroll
  for (int kt = 0; kt < 10; ++kt){
    if (kt < 9){
      STAGE((kt + 1) & 1, kt + 1);
      asm volatile("s_waitcnt vmcnt(4)" ::: "memory");
    } else {
      asm volatile("s_waitcnt vmcnt(0)" ::: "memory");
    }
    __builtin_amdgcn_s_barrier();
    __builtin_amdgcn_sched_barrier(0);
    char* bA = smem + (kt & 1) * 16384;
    char* bB = bA + 8192;
    bf16x8 af[4], bg[4];
    #pragma unroll
    for (int i = 0; i < 4; ++i){
      int row = wv * 64 + i * 16 + lrow;
      af[i] = *(const bf16x8*)(bA + row * 64 + (lq ^ ((row >> 1) & 3)) * 16);
    }
    #pragma unroll
    for (int j = 0; j < 4; ++j){
      int row = wm * 64 + j * 16 + lrow;
      bg[j] = *(const bf16x8*)(bB + row * 64 + (lq ^ ((row >> 1) & 3)) * 16);
    }
    #pragma unroll
    for (int i = 0; i < 4; ++i)
      #pragma unroll
      for (int j = 0; j < 4; ++j)
        acc[i][j] = __builtin_amdgcn_mfma_f32_16x16x32_bf16(af[i], bg[j], acc[i][j], 0, 0, 0);
    __builtin_amdgcn_sched_barrier(0);
    __builtin_amdgcn_s_barrier();
  }

  // bias per thread's 4 col-groups
  float bv4[4];
  #pragma unroll
  for (int j = 0; j < 4; ++j){
    int mg = m0 + wm * 64 + j * 16 + lrow;
    bv4[j] = (mg < 2100) ? bias[mg] : 0.f;
  }
  // epilogue: regs -> bf16 LDS [128][132] -> coalesced uint2 stores
  unsigned short* eb = (unsigned short*)smem;
  #pragma unroll
  for (int i = 0; i < 4; ++i)
    #pragma unroll
    for (int j = 0; j < 4; ++j)
      #pragma unroll
      for (int r = 0; r < 4; ++r){
        int row = wv * 64 + i * 16 + lq * 4 + r;
        int col = wm * 64 + j * 16 + lrow;
        eb[row * 132 + col] = f2bf(acc[i][j][r] + bv4[j]);
      }
  __syncthreads();
  #pragma unroll
  for (int it = 0; it < 16; ++it){
    int idx2 = it * 256 + tid;
    int row = idx2 >> 5, ch = idx2 & 31;   // ch: 8-byte units (4 bf16)
    int vg = v0 + row, mg = m0 + ch * 4;
    if (vg < V_ && mg < MP){
      uint2 val = *(const uint2*)(smem + row * 264 + ch * 8);
      *(uint2*)&trans[(size_t)vg * MP + mg] = val;
    }
  }
}

// ---------------- K3: chunked affine max-plus scan
// per (b, chunk, p): fold 64 steps into (A cols tri-28, b 7, u 7, w 1) -> chunkout[...][44]
// distance-3 software-pipelined prefetch with named register sets (no runtime indexing)
__global__ __launch_bounds__(192) void k_scan(const unsigned short* __restrict__ trans,
                                              const int* __restrict__ docs,
                                              const int* __restrict__ doc_lens,
                                              const float* __restrict__ epsilon,
                                              float* __restrict__ chunkout){
  __shared__ int sdocs[CHUNK];
  int b = blockIdx.x >> 5, ch = blockIdx.x & 31;
  int tid = threadIdx.x;
  if (tid < CHUNK) sdocs[tid] = docs[b * T_ + ch * CHUNK + tid];
  __syncthreads();
  int p = tid;
  if (p >= P_) return;
  int doclen = doc_lens[b];
  float eps_r[6];
  #pragma unroll
  for (int i = 0; i < 6; ++i) eps_r[i] = epsilon[p*6 + i];
  int endsel = p / 50;   // 0,1,2 -> end state 4,5,6

  float col[7][7], bvec[7], uvec[7], w;
  #pragma unroll
  for (int j = 0; j < 7; ++j)
    #pragma unroll
    for (int l = 0; l < 7; ++l) col[j][l] = (j == l) ? 0.f : NEGC;
  #pragma unroll
  for (int l = 0; l < 7; ++l){ bvec[l] = NEGC; uvec[l] = NEGC; }
  w = NEGC;

  const char* transB = (const char*)trans;

  auto LOADQ = [&](unsigned* q, int s){
    int idx = s < 63 ? s : 63;
    const unsigned* rp = (const unsigned*)(transB + (size_t)sdocs[idx] * (MP*2) + p*28);
    #pragma unroll
    for (int i = 0; i < 7; ++i) q[i] = rp[i];
  };

  auto step = [&](const unsigned* q, bool act){
    float tsf[7], tmn[6];
    tsf[0]=bf_lo(q[0]); tsf[1]=bf_hi(q[0]);
    tsf[2]=bf_lo(q[1]); tsf[3]=bf_hi(q[1]);
    tsf[4]=bf_lo(q[2]); tsf[5]=bf_hi(q[2]);
    tsf[6]=bf_lo(q[3]); tmn[0]=bf_hi(q[3]);
    tmn[1]=bf_lo(q[4]); tmn[2]=bf_hi(q[4]);
    tmn[3]=bf_lo(q[5]); tmn[4]=bf_hi(q[5]);
    tmn[5]=bf_lo(q[6]);
    // linear part: update each (triangular) column, descending l so old values are read
    #pragma unroll
    for (int j = 0; j < 7; ++j){
      #pragma unroll
      for (int l = 6; l >= 1; --l){
        if (l < j) continue;
        if (l == j){ col[j][l] = col[j][l] + tsf[l]; continue; }
        float ae;
        if (l - 1 == j) ae = col[j][l-1];
        else ae = fmaxf(col[j][l-1], col[j][l-2] + eps_r[l-2]);
        col[j][l] = fmaxf(ae + tmn[l-1], col[j][l] + tsf[l]);
      }
      if (j == 0) col[0][0] += tsf[0];
    }
    // const part: full reference map incl. restart(0) and zero_pad(-100)
    #pragma unroll
    for (int l = 6; l >= 1; --l){
      float ae;
      if (l == 1) ae = fmaxf(bvec[0], -100.0f);
      else ae = fmaxf(bvec[l-1], bvec[l-2] + eps_r[l-2]);
      bvec[l] = fmaxf(ae + tmn[l-1], bvec[l] + tsf[l]);
    }
    bvec[0] = fmaxf(0.0f, bvec[0] + tsf[0]);
    if (act){
      #pragma unroll
      for (int j = 0; j < 7; ++j){
        float c4 = (j <= 4) ? col[j][4] : NEGC;
        float c5 = (j <= 5) ? col[j][5] : NEGC;
        float c6 = col[j][6];
        float ce = (endsel == 0) ? c4 : ((endsel == 1) ? c5 : c6);
        uvec[j] = fmaxf(uvec[j], ce);
      }
      float be = (endsel == 0) ? bvec[4] : ((endsel == 1) ? bvec[5] : bvec[6]);
      w = fmaxf(w, be);
    }
  };

  unsigned q0[7], q1[7], q2[7], q3[7];
  LOADQ(q0, 0); LOADQ(q1, 1); LOADQ(q2, 2);
  int tbase = ch * CHUNK;
  for (int s = 0; s < CHUNK; s += 4){
    LOADQ(q3, s + 3); step(q0, (tbase + s)     < doclen);
    LOADQ(q0, s + 4); step(q1, (tbase + s + 1) < doclen);
    LOADQ(q1, s + 5); step(q2, (tbase + s + 2) < doclen);
    LOADQ(q2, s + 6); step(q3, (tbase + s + 3) < doclen);
  }

  float out[44];
  int idx = 0;
  #pragma unroll
  for (int j = 0; j < 7; ++j)
    #pragma unroll
    for (int l = j; l < 7; ++l) out[idx++] = col[j][l];
  #pragma unroll
  for (int l = 0; l < 7; ++l) out[28 + l] = bvec[l];
  #pragma unroll
  for (int l = 0; l < 7; ++l) out[35 + l] = uvec[l];
  out[42] = w; out[43] = 0.f;
  float* dst = chunkout + ((size_t)(b * NCH + ch) * P_ + p) * 44;
  #pragma unroll
  for (int i = 0; i < 11; ++i){
    float4 t2 = make_float4(out[4*i], out[4*i+1], out[4*i+2], out[4*i+3]);
    ((float4*)dst)[i] = t2;
  }
}

// ---------------- K45: per-(b,p) fold of 32 chunks + MLP head
__global__ __launch_bounds__(192) void k_combine_mlp(const float* __restrict__ chunkout,
                                                     const float* __restrict__ w0,
                                                     const float* __restrict__ b0,
                                                     const float* __restrict__ w1,
                                                     const float* __restrict__ b1,
                                                     float* __restrict__ out){
  __shared__ float ssc[P_];
  __shared__ float sh[100];
  int b = blockIdx.x, tid = threadIdx.x;
  if (tid < P_){
    int p = tid;
    float h[7] = {0.f, -100.f, -100.f, -100.f, -100.f, -100.f, -100.f};
    float sc = -100.f;
    for (int ch = 0; ch < NCH; ++ch){
      const float* rec = chunkout + ((size_t)(b * NCH + ch) * P_ + p) * 44;
      float r[44];
      #pragma unroll
      for (int i = 0; i < 11; ++i){
        float4 t = ((const float4*)rec)[i];
        r[4*i] = t.x; r[4*i+1] = t.y; r[4*i+2] = t.z; r[4*i+3] = t.w;
      }
      // score with OLD h (u . h, w)
      #pragma unroll
      for (int j = 0; j < 7; ++j) sc = fmaxf(sc, r[35 + j] + h[j]);
      sc = fmaxf(sc, r[42]);
      // h' = A (x) h  (+)  b
      constexpr int off[7] = {0, 7, 13, 18, 22, 25, 27};
      float nh[7];
      #pragma unroll
      for (int l = 0; l < 7; ++l){
        float v = r[28 + l];
        #pragma unroll
        for (int j = 0; j < 7; ++j){
          if (j <= l) v = fmaxf(v, r[off[j] + (l - j)] + h[j]);
        }
        nh[l] = v;
      }
      #pragma unroll
      for (int l = 0; l < 7; ++l) h[l] = nh[l];
    }
    ssc[p] = sc;
  }
  __syncthreads();
  if (tid < 100){
    float a = b0[tid];
    for (int pp = 0; pp < P_; ++pp) a += ssc[pp] * w0[pp * 100 + tid];
    sh[tid] = fmaxf(a, 0.f);
  }
  __syncthreads();
  if (tid < 2){
    float o = b1[tid];
    for (int j = 0; j < 100; ++j) o += sh[j] * w1[j * 2 + tid];
    out[b * 2 + tid] = o;
  }
}

extern "C" void kernel_launch(void* const* d_in, const int* in_sizes, int n_in,
                              void* d_out, int out_size, void* d_ws, size_t ws_size,
                              hipStream_t stream){
  const float* emb   = (const float*)d_in[0];   // [300][50000]
  const float* diags = (const float*)d_in[1];   // [2100][300]
  const float* bias  = (const float*)d_in[2];   // [2100]
  const float* eps   = (const float*)d_in[3];   // [150][6]
  const float* w0    = (const float*)d_in[4];   // [150][100]
  const float* b0    = (const float*)d_in[5];   // [100]
  const float* w1    = (const float*)d_in[6];   // [100][2]
  const float* b1    = (const float*)d_in[7];   // [2]
  const int* docs    = (const int*)d_in[8];     // [32][2048]
  const int* dlens   = (const int*)d_in[9];     // [32]

  if (ws_size < (size_t)WS_NEEDED) return;   // diagnostic: all-zero output => ws too small

  char* ws = (char*)d_ws;
  unsigned short* embT   = (unsigned short*)(ws + WS_EMBT);
  unsigned short* diagsB = (unsigned short*)(ws + WS_DIAGSB);
  unsigned short* trans  = (unsigned short*)(ws + WS_TRANS);
  float* chunkout        = (float*)(ws + WS_CHUNKOUT);   // aliases embT (dead after k_gemm)
  float* outp = (float*)d_out;

  k_transpose_emb<<<dim3(NPAD/64, KP/32), 256, 0, stream>>>(emb, embT);
  k_conv_diags<<<(MB2*80 + 255)/256, 256, 0, stream>>>(diags, diagsB);
  k_gemm<<<NWG, 256, 0, stream>>>(embT, diagsB, bias, trans);
  k_scan<<<B_ * NCH, 192, 0, stream>>>(trans, docs, dlens, eps, chunkout);
  k_combine_mlp<<<B_, 192, 0, stream>>>(chunkout, w0, b0, w1, b1, outp);
}